// Round 2
// baseline (205.945 us; speedup 1.0000x reference)
//
#include <hip/hip_runtime.h>

#define K_NEIGH 32
#define D_FEAT  128
#define RPP     8        // rows staged per pass
#define NPASS   4        // K_NEIGH / RPP
#define RSTRIDE 132      // floats per LDS row slot (528 B, 16B-aligned, padded)
#define WPB     4        // waves per block (block = 256)

__device__ __forceinline__ float readlane_f(float v, int l) {
    return __int_as_float(__builtin_amdgcn_readlane(__float_as_int(v), l));
}

// One wave per batch element. LDS is wave-private (no __syncthreads needed:
// per-wave DS ops are processed in order).
__global__ __launch_bounds__(256, 6) void intra_agg_kernel(
    const float* __restrict__ features,
    const int*   __restrict__ nodes,
    const int*   __restrict__ neighs,
    const int*   __restrict__ num_sample_p,
    float*       __restrict__ out,
    int batch)
{
    __shared__ float s_rows[WPB][RPP * RSTRIDE];  // 4224 B / wave
    __shared__ float s_cen [WPB][D_FEAT];         //  512 B / wave

    const int tid  = blockIdx.x * blockDim.x + threadIdx.x;
    const int b    = tid >> 6;
    const int w    = threadIdx.x >> 6;
    const int lane = threadIdx.x & 63;
    const int l32  = lane & 31;
    const int half = lane >> 5;
    if (b >= batch) return;

    const int ns = *num_sample_p;
    const int* nb = neighs + (size_t)b * K_NEIGH;

    // ---- center: load (coalesced, both halves), norm via 5-step butterfly, park in LDS
    const int   cnode = nodes[b];
    const float4 c4 = ((const float4*)(features + (size_t)cnode * D_FEAT))[l32];
    float c2 = c4.x*c4.x + c4.y*c4.y + c4.z*c4.z + c4.w*c4.w;
    #pragma unroll
    for (int m = 16; m >= 1; m >>= 1) c2 += __shfl_xor(c2, m);
    const float cn = sqrtf(c2);
    if (half == 0) ((float4*)s_cen[w])[l32] = c4;

    // Dot-phase lane roles: row kk (0..7) within pass, dim-chunk jj (16 dims each).
    const int kk = lane & 7;
    const int jj = lane >> 3;     // 0..7

    // Hoist this lane's 16 center dims out of the pass loop (broadcast LDS reads).
    float4 cfrag[4];
    #pragma unroll
    for (int t = 0; t < 4; ++t)
        cfrag[t] = *(const float4*)(s_cen[w] + jj * 16 + 4 * t);

    float dotv[NPASS], nn2v[NPASS];
    #pragma unroll
    for (int p = 0; p < NPASS; ++p) {
        // stage 8 rows: halves load rows 2i / 2i+1 coalesced, write to LDS
        #pragma unroll
        for (int i = 0; i < 4; ++i) {
            const int lr   = 2 * i + half;                 // local row 0..7
            const int nidx = nb[p * RPP + lr];             // 2 addrs/wave, L1 broadcast
            const float4 r = ((const float4*)(features + (size_t)nidx * D_FEAT))[l32];
            ((float4*)(s_rows[w] + lr * RSTRIDE))[l32] = r;
        }
        // dot + ||n||^2 for row kk over dims [16*jj, 16*jj+16)
        float d = 0.f, n = 0.f;
        #pragma unroll
        for (int t = 0; t < 4; ++t) {
            const float4 r  = *(const float4*)(s_rows[w] + kk * RSTRIDE + jj * 16 + 4 * t);
            const float4 cc = cfrag[t];
            d += cc.x*r.x + cc.y*r.y + cc.z*r.z + cc.w*r.w;
            n +=  r.x*r.x +  r.y*r.y +  r.z*r.z +  r.w*r.w;
        }
        // reduce over the 8 replicas (lanes kk, kk+8, ..., kk+56): 3 steps only
        d += __shfl_xor(d, 8);  n += __shfl_xor(n, 8);
        d += __shfl_xor(d, 16); n += __shfl_xor(n, 16);
        d += __shfl_xor(d, 32); n += __shfl_xor(n, 32);
        dotv[p] = d; nn2v[p] = n;
    }

    // Lane l holds rows {8p + (l&7)}; row (l&31) lives at p = (l&31)>>3.
    const int psel = l32 >> 3;
    float mydot = dotv[0], myn2 = nn2v[0];
    if (psel == 1) { mydot = dotv[1]; myn2 = nn2v[1]; }
    if (psel == 2) { mydot = dotv[2]; myn2 = nn2v[2]; }
    if (psel == 3) { mydot = dotv[3]; myn2 = nn2v[3]; }
    const float sim = mydot / (cn * sqrtf(myn2));   // lane l: sim of row l&31

    // Stable rank via scalar readlane broadcasts (no LDS ops):
    // rank = #{j: s_j > s_k} + #{j<k: s_j == s_k}
    int rank = 0;
    #pragma unroll
    for (int j = 0; j < 32; ++j) {
        const float sj = readlane_f(sim, j);        // duplicated halves -> lane j ok
        rank += (sj > sim || (sj == sim && j < l32)) ? 1 : 0;
    }
    const bool sel = (rank < ns);
    const unsigned mask = (unsigned)(__ballot(sel) & 0xffffffffull);

    // Mean of selected rows: wave-uniform bit-scan loop, coalesced float2 re-gather
    // (rows are L1/L2-hot from the dot phase).
    float2 acc = make_float2(0.f, 0.f);
    unsigned mrem = mask;
    while (mrem) {
        const int j = __ffs(mrem) - 1;
        mrem &= mrem - 1;
        const int nidx = nb[j];                     // uniform addr, L1 broadcast
        const float2 r = ((const float2*)(features + (size_t)nidx * D_FEAT))[lane];
        acc.x += r.x; acc.y += r.y;
    }
    const float nsf = (float)ns;
    float2 o;
    o.x = fmaxf(acc.x / nsf, 0.f);
    o.y = fmaxf(acc.y / nsf, 0.f);
    ((float2*)(out + (size_t)b * D_FEAT))[lane] = o;
}

extern "C" void kernel_launch(void* const* d_in, const int* in_sizes, int n_in,
                              void* d_out, int out_size, void* d_ws, size_t ws_size,
                              hipStream_t stream) {
    const float* features = (const float*)d_in[0];
    const int*   nodes    = (const int*)d_in[1];
    const int*   neighs   = (const int*)d_in[2];
    const int*   ns       = (const int*)d_in[3];
    float*       out      = (float*)d_out;

    const int batch  = in_sizes[1];            // 32768
    const int blocks = (batch + WPB - 1) / WPB;

    intra_agg_kernel<<<blocks, 256, 0, stream>>>(features, nodes, neighs, ns, out, batch);
}

// Round 3
// 153.407 us; speedup vs baseline: 1.3425x; 1.3425x over previous
//
#include <hip/hip_runtime.h>

#define K_NEIGH 32
#define D_FEAT  128

__device__ __forceinline__ float readlane_f(float v, int l) {
    return __int_as_float(__builtin_amdgcn_readlane(__float_as_int(v), l));
}

// One wave per batch element. Lane l owns dims {2l, 2l+1} (float2).
// All 32 neighbor rows live in registers; reduction via 6-step fold
// (32 shuffles per quantity); no LDS at all.
__global__ __launch_bounds__(256, 3) void intra_agg_kernel(
    const float* __restrict__ features,
    const int*   __restrict__ nodes,
    const int*   __restrict__ neighs,
    const int*   __restrict__ num_sample_p,
    float*       __restrict__ out,
    int batch)
{
    const int tid  = blockIdx.x * blockDim.x + threadIdx.x;
    const int lane = threadIdx.x & 63;
    int b = tid >> 6;
    if (b >= batch) return;
    b = __builtin_amdgcn_readfirstlane(b);   // force scalar index loads

    const int  ns = *num_sample_p;
    const int* nb = neighs + (size_t)b * K_NEIGH;

    // Center fragment (coalesced 512B across the wave).
    const int   cnode = nodes[b];
    const float2 c2 = ((const float2*)(features + (size_t)cnode * D_FEAT))[lane];

    // All 32 neighbor rows: independent coalesced float2 loads -> registers.
    float2 rows[K_NEIGH];
    #pragma unroll
    for (int r = 0; r < K_NEIGH; ++r) {
        const int nidx = nb[r];              // wave-uniform -> s_load
        rows[r] = ((const float2*)(features + (size_t)nidx * D_FEAT))[lane];
    }

    // ||center|| via 6-step butterfly.
    float cc = c2.x * c2.x + c2.y * c2.y;
    #pragma unroll
    for (int m = 32; m >= 1; m >>= 1) cc += __shfl_xor(cc, m);
    const float cn = sqrtf(cc);

    // Per-lane partials for all 32 rows.
    float dt[K_NEIGH], n2[K_NEIGH];
    #pragma unroll
    for (int r = 0; r < K_NEIGH; ++r) {
        dt[r] = c2.x * rows[r].x + c2.y * rows[r].y;
        n2[r] = rows[r].x * rows[r].x + rows[r].y * rows[r].y;
    }

    // Fold: each step halves values-per-lane and lanes-per-value.
    // After o=2, lane l holds row (l>>1)'s full sums over 2 lanes; o=1 finishes.
    #pragma unroll
    for (int o = 32; o >= 2; o >>= 1) {
        const bool up = (lane & o) != 0;
        #pragma unroll
        for (int r = 0; r < o / 2; ++r) {
            const float sd = up ? dt[r] : dt[r + o / 2];
            const float sn = up ? n2[r] : n2[r + o / 2];
            const float rd = __shfl_xor(sd, o);
            const float rn = __shfl_xor(sn, o);
            const float kd = up ? dt[r + o / 2] : dt[r];
            const float kn = up ? n2[r + o / 2] : n2[r];
            dt[r] = kd + rd;
            n2[r] = kn + rn;
        }
    }
    dt[0] += __shfl_xor(dt[0], 1);
    n2[0] += __shfl_xor(n2[0], 1);

    const int   myrow = lane >> 1;           // row whose sim this lane holds
    const float sim   = dt[0] / (cn * sqrtf(n2[0]));

    // Stable rank (matches lax.top_k): readlane broadcasts, VALU only.
    int rank = 0;
    #pragma unroll
    for (int j = 0; j < K_NEIGH; ++j) {
        const float sj = readlane_f(sim, 2 * j);
        rank += (sj > sim || (sj == sim && j < myrow)) ? 1 : 0;
    }

    // Ballot has sel_r duplicated at bits 2r, 2r+1 -> compress even bits.
    const unsigned long long bal = __ballot(rank < ns);
    unsigned long long x = bal & 0x5555555555555555ull;
    x = (x | (x >> 1))  & 0x3333333333333333ull;
    x = (x | (x >> 2))  & 0x0F0F0F0F0F0F0F0Full;
    x = (x | (x >> 4))  & 0x00FF00FF00FF00FFull;
    x = (x | (x >> 8))  & 0x0000FFFF0000FFFFull;
    x = (x | (x >> 16)) & 0x00000000FFFFFFFFull;
    const unsigned mask = (unsigned)x;       // bit r = row r selected

    // Mean over selected rows from registers: predicated FMA, zero loads.
    float2 acc = make_float2(0.f, 0.f);
    #pragma unroll
    for (int r = 0; r < K_NEIGH; ++r) {
        const float s = (float)((mask >> r) & 1u);
        acc.x = fmaf(rows[r].x, s, acc.x);
        acc.y = fmaf(rows[r].y, s, acc.y);
    }
    const float nsf = (float)ns;
    float2 ov;
    ov.x = fmaxf(acc.x / nsf, 0.f);
    ov.y = fmaxf(acc.y / nsf, 0.f);
    ((float2*)(out + (size_t)b * D_FEAT))[lane] = ov;
}

extern "C" void kernel_launch(void* const* d_in, const int* in_sizes, int n_in,
                              void* d_out, int out_size, void* d_ws, size_t ws_size,
                              hipStream_t stream) {
    const float* features = (const float*)d_in[0];
    const int*   nodes    = (const int*)d_in[1];
    const int*   neighs   = (const int*)d_in[2];
    const int*   ns       = (const int*)d_in[3];
    float*       out      = (float*)d_out;

    const int batch  = in_sizes[1];            // 32768
    const int blocks = (batch + 3) / 4;        // 4 waves per 256-thread block

    intra_agg_kernel<<<blocks, 256, 0, stream>>>(features, nodes, neighs, ns, out, batch);
}